// Round 1
// baseline (1165.688 us; speedup 1.0000x reference)
//
#include <hip/hip_runtime.h>
#include <hip/hip_bf16.h>
#include <stdint.h>

#define DD 32
#define KH 96   // 3*D

// ws layout:
//  hdr (uint32):
//   [0] idx_mode  (0 = int64, 1 = int32)
//   [1] sel_mode  (0 = int64, 1 = int32, 2 = bytes)
//   [2] fmode     (0 = bf16 floats, 1 = fp32 floats)
//   [3] min_key   (encoded float, atomicMin over ALL state_prob)
//   [4] max_key   (encoded float, atomicMax over UNSELECTED state_prob)
//   [5] cnt_unsel
//   [6] sum       (float bits, atomicAdd)
//  ws+256    : float Wf[3072]
//  ws+12544  : float bf[32]
//  ws+12672  : float vf[32]
//  ws+16384  : float sp[E]   (only if ws_size permits; else sp lives in d_out)

typedef __attribute__((ext_vector_type(16))) float vf16;

__device__ __forceinline__ uint32_t fkey(float f) {
    uint32_t b = __float_as_uint(f);
    return (b & 0x80000000u) ? ~b : (b | 0x80000000u);
}
__device__ __forceinline__ float funkey(uint32_t k) {
    uint32_t b = (k & 0x80000000u) ? (k & 0x7FFFFFFFu) : ~k;
    return __uint_as_float(b);
}
__device__ __forceinline__ float bflo(uint32_t w) { return __uint_as_float(w << 16); }
__device__ __forceinline__ float bfhi(uint32_t w) { return __uint_as_float(w & 0xFFFF0000u); }
__device__ __forceinline__ uint16_t f2bf(float v) {
    uint32_t u = __float_as_uint(v);
    uint32_t r = (u + 0x7FFFu + ((u >> 16) & 1u)) >> 16;
    return (uint16_t)r;
}

// wave-uniform scalar load of 32 consecutive floats into SGPRs (full drain; used
// only outside the hot loop: bias and v vectors)
__device__ __forceinline__ void wload(const float* p, vf16& a, vf16& b) {
    asm volatile("s_load_dwordx16 %0, %2, 0x0\n\t"
                 "s_load_dwordx16 %1, %2, 0x40\n\t"
                 "s_waitcnt lgkmcnt(0)"
                 : "=&s"(a), "=&s"(b)
                 : "s"(p));
}

// --- pipelined scalar W stream ---------------------------------------------
// issue a 64B scalar load (no wait).  IMM must be an integer constant
// expression — all call sites use literal-folded macro constants.
#define SLOAD16(dst, base, imm) \
    asm volatile("s_load_dwordx16 %0, %1, %2" : "=&s"(dst) : "s"(base), "i"(imm))

// drain: SMEM completions are unordered, so only a full lgkmcnt(0) drain is
// safe — the pipeline keeps exactly ONE load in flight so the drain is exact.
__device__ __forceinline__ void swait16(vf16& a) {
    asm volatile("s_waitcnt lgkmcnt(0)" : "+s"(a));
}

// 16 × v_fmac_f32 vacc, sW, vh — SGPR folded into src0 (VOP2-legal), no v_mov.
#define FMAC(d, s, h) asm("v_fmac_f32 %0, %1, %2" : "+v"(d) : "s"(s), "v"(h))

__device__ __forceinline__ void fma16(float* accp, const vf16& w, float hk) {
    #pragma unroll
    for (int j = 0; j < 16; ++j) FMAC(accp[j], w[j], hk);
}

// One pipelined double-chunk step: A holds chunk c (row c>>1, half c&1).
// issue(c+1) -> 16 FMA on A (32 cyc of cover) -> drain -> issue(c+2) -> 16 FMA
// on B -> drain.  FMA accumulation order per acc[j] is identical to the
// baseline kernel (k ascending), so results are bit-identical.
#define STEP2(c)                                                        \
    {                                                                   \
        SLOAD16(B, wp, ((c) + 1) * 64);                                 \
        fma16(acc + (((c) & 1) * 16), A, hh[(c) >> 1]);                 \
        swait16(B);                                                     \
        if ((c) + 2 < 64) { SLOAD16(A, wp, ((c) + 2) * 64); }           \
        fma16(acc + ((((c) + 1) & 1) * 16), B, hh[((c) + 1) >> 1]);     \
        if ((c) + 2 < 64) { swait16(A); }                               \
    }

__global__ void k_init(const void* W, const void* bias, const void* g, const void* sg,
                       const void* ei, const void* sel,
                       uint32_t* hdr, float* Wf, float* bf, float* vf, int E, int N) {
    int t = threadIdx.x;
    __shared__ int sh_i32, sh_gt1, sh_odd, sh_f32;
    if (t == 0) { sh_i32 = 0; sh_gt1 = 0; sh_odd = 0; sh_f32 = 0; }
    __syncthreads();

    const uint16_t* wb = (const uint16_t*)W;
    for (int i = t; i < KH * DD; i += 256) {
        float x = bflo((uint32_t)wb[i]);
        if (!(fabsf(x) < 1e4f)) sh_f32 = 1;
    }
    const long long* ell = (const long long*)ei;
    int ns = 2048 < E ? 2048 : E;
    for (int i = t; i < ns; i += 256) {
        long long v = ell[i];
        if (v < 0 || v >= (long long)N) sh_i32 = 1;
    }
    const uint32_t* sw = (const uint32_t*)sel;
    int ns2 = 2048 < E / 4 ? 2048 : E / 4;
    for (int i = t; i < ns2; i += 256) {
        uint32_t v = sw[i];
        if (v > 1u) sh_gt1 = 1;
        if (v != 0u && (i & 1)) sh_odd = 1;
    }
    __syncthreads();
    int fmode = sh_f32;

    for (int i = t; i < KH * DD; i += 256)
        Wf[i] = fmode ? ((const float*)W)[i] : bflo((uint32_t)wb[i]);
    for (int i = t; i < DD; i += 256) {
        bf[i] = fmode ? ((const float*)bias)[i] : bflo((uint32_t)((const uint16_t*)bias)[i]);
        float gv = fmode ? ((const float*)g)[i]  : bflo((uint32_t)((const uint16_t*)g)[i]);
        float sv = fmode ? ((const float*)sg)[i] : bflo((uint32_t)((const uint16_t*)sg)[i]);
        vf[i] = gv - sv;
    }
    if (t == 0) {
        hdr[0] = (uint32_t)sh_i32;
        hdr[1] = sh_gt1 ? 2u : (sh_odd ? 1u : 0u);
        hdr[2] = (uint32_t)fmode;
        hdr[3] = 0xFFFFFFFFu;
        hdr[4] = 0u;
        hdr[5] = 0u;
        hdr[6] = 0u;
    }
}

__device__ __forceinline__ void loadrow(const char* __restrict__ p, int fmode, float* h) {
    if (fmode) {
        const float4* q = (const float4*)p;
        #pragma unroll
        for (int t = 0; t < 8; ++t) {
            float4 u = q[t];
            h[t * 4 + 0] = u.x; h[t * 4 + 1] = u.y; h[t * 4 + 2] = u.z; h[t * 4 + 3] = u.w;
        }
    } else {
        const uint4* q = (const uint4*)p;
        #pragma unroll
        for (int t = 0; t < 4; ++t) {
            uint4 u = q[t];
            h[t * 8 + 0] = bflo(u.x); h[t * 8 + 1] = bfhi(u.x);
            h[t * 8 + 2] = bflo(u.y); h[t * 8 + 3] = bfhi(u.y);
            h[t * 8 + 4] = bflo(u.z); h[t * 8 + 5] = bfhi(u.z);
            h[t * 8 + 6] = bflo(u.w); h[t * 8 + 7] = bfhi(u.w);
        }
    }
}

__device__ __forceinline__ bool fetch_sel(const char* sel, int mode, int e) {
    if (mode == 2) return ((const uint8_t*)sel)[e] != 0;
    if (mode == 1) return ((const int*)sel)[e] != 0;
    return ((const long long*)sel)[e] != 0;
}

__device__ __forceinline__ void sp_store(float* __restrict__ ws_sp, void* __restrict__ out,
                                         int use_ws, int fmode, int e, float v) {
    if (use_ws) ws_sp[e] = v;
    else if (fmode) ((float*)out)[e] = v;
    else ((uint16_t*)out)[e] = f2bf(v);
}
__device__ __forceinline__ float sp_load(const float* __restrict__ ws_sp, const void* __restrict__ out,
                                         int use_ws, int fmode, int e) {
    if (use_ws) return ws_sp[e];
    if (fmode) return ((const float*)out)[e];
    return bflo((uint32_t)((const uint16_t*)out)[e]);
}

__global__ __launch_bounds__(256) void k_pass1(
    const char* __restrict__ node, const char* __restrict__ edgep,
    const char* __restrict__ ei, const char* __restrict__ sel,
    uint32_t* __restrict__ hdr, const float* __restrict__ Wf,
    const float* __restrict__ bf, const float* __restrict__ vf,
    float* __restrict__ ws_sp, void* __restrict__ out,
    int use_ws, int E, int N) {
    const int idx_mode = (int)hdr[0];
    const int sel_mode = (int)hdr[1];
    const int fmode    = (int)hdr[2];

    int e = blockIdx.x * 256 + threadIdx.x;
    bool valid = e < E;
    int ec = valid ? e : E - 1;

    long long si, di;
    if (idx_mode) { si = ((const int*)ei)[ec]; di = ((const int*)ei)[E + ec]; }
    else          { si = ((const long long*)ei)[ec]; di = ((const long long*)ei)[(size_t)E + ec]; }
    int s0 = (int)si; s0 = s0 < 0 ? 0 : (s0 >= N ? N - 1 : s0);
    int d0 = (int)di; d0 = d0 < 0 ? 0 : (d0 >= N ? N - 1 : d0);

    size_t rb = fmode ? 128 : 64;
    const char* p0 = node  + (size_t)s0 * rb;
    const char* p1 = node  + (size_t)d0 * rb;
    const char* p2 = edgep + (size_t)ec * rb;

    // acc init from bias (scalar-loaded, wave-uniform)
    float acc[DD];
    {
        vf16 b0, b1;
        wload(bf, b0, b1);
        #pragma unroll
        for (int j = 0; j < 16; ++j) { acc[j] = b0[j]; acc[16 + j] = b1[j]; }
    }

    float hh[32], hn[32];
    loadrow(p0, fmode, hh);

    #pragma unroll 1
    for (int r = 0; r < 3; ++r) {
        if (r < 2) {
            const char* pn = (r == 0) ? p1 : p2;
            loadrow(pn, fmode, hn);
        }
        const float* wp = Wf + r * 32 * DD;
        vf16 A, B;
        SLOAD16(A, wp, 0);
        swait16(A);
        STEP2(0)  STEP2(2)  STEP2(4)  STEP2(6)
        STEP2(8)  STEP2(10) STEP2(12) STEP2(14)
        STEP2(16) STEP2(18) STEP2(20) STEP2(22)
        STEP2(24) STEP2(26) STEP2(28) STEP2(30)
        STEP2(32) STEP2(34) STEP2(36) STEP2(38)
        STEP2(40) STEP2(42) STEP2(44) STEP2(46)
        STEP2(48) STEP2(50) STEP2(52) STEP2(54)
        STEP2(56) STEP2(58) STEP2(60) STEP2(62)
        if (r < 2) {
            #pragma unroll
            for (int k = 0; k < 32; ++k) hh[k] = hn[k];
        }
    }

    float sp = 0.f;
    {
        vf16 v0, v1;
        wload(vf, v0, v1);
        #pragma unroll
        for (int j = 0; j < 16; ++j) {
            float a = acc[j];
            float act = a > 0.f ? a : (__expf(a) - 1.f);
            sp = fmaf(act, v0[j], sp);
            float a2 = acc[16 + j];
            float act2 = a2 > 0.f ? a2 : (__expf(a2) - 1.f);
            sp = fmaf(act2, v1[j], sp);
        }
    }

    bool selv = true;
    if (valid) {
        sp_store(ws_sp, out, use_ws, fmode, e, sp);
        selv = fetch_sel(sel, sel_mode, e);
    }

    float mn = valid ? sp : __builtin_inff();
    float mx = (valid && !selv) ? sp : -__builtin_inff();
    uint32_t c = (valid && !selv) ? 1u : 0u;
    #pragma unroll
    for (int o = 32; o >= 1; o >>= 1) {
        mn = fminf(mn, __shfl_xor(mn, o));
        mx = fmaxf(mx, __shfl_xor(mx, o));
        c += __shfl_xor(c, o);
    }
    __shared__ float smn[4], smx[4];
    __shared__ uint32_t sc[4];
    int wid = threadIdx.x >> 6, lane = threadIdx.x & 63;
    if (lane == 0) { smn[wid] = mn; smx[wid] = mx; sc[wid] = c; }
    __syncthreads();
    if (threadIdx.x == 0) {
        for (int w = 1; w < 4; ++w) { mn = fminf(mn, smn[w]); mx = fmaxf(mx, smx[w]); c += sc[w]; }
        atomicMin(&hdr[3], fkey(mn));
        atomicMax(&hdr[4], fkey(mx));
        if (c) atomicAdd(&hdr[5], c);
    }
}

__global__ __launch_bounds__(256) void k_pass2(
    const char* __restrict__ sel, uint32_t* __restrict__ hdr,
    const float* __restrict__ ws_sp, const void* __restrict__ out,
    int use_ws, int E) {
    int e = blockIdx.x * 256 + threadIdx.x;
    int sel_mode = (int)hdr[1], fmode = (int)hdr[2];
    float mn = funkey(hdr[3]);
    uint32_t cnt = hdr[5];
    float M = cnt ? funkey(hdr[4]) : mn;
    float p = 0.f;
    if (e < E) {
        float sp = sp_load(ws_sp, out, use_ws, fmode, e);
        bool selv = fetch_sel(sel, sel_mode, e);
        float masked = selv ? mn : sp;
        p = __expf((masked - M) * 2.0f);
    }
    #pragma unroll
    for (int o = 32; o >= 1; o >>= 1) p += __shfl_xor(p, o);
    __shared__ float sps[4];
    int wid = threadIdx.x >> 6, lane = threadIdx.x & 63;
    if (lane == 0) sps[wid] = p;
    __syncthreads();
    if (threadIdx.x == 0) {
        p += sps[1] + sps[2] + sps[3];
        atomicAdd((float*)&hdr[6], p);
    }
}

__global__ __launch_bounds__(256) void k_pass3(
    const char* __restrict__ sel, const uint32_t* __restrict__ hdr,
    const float* __restrict__ ws_sp, void* __restrict__ out,
    int use_ws, int E) {
    int e = blockIdx.x * 256 + threadIdx.x;
    if (e >= E) return;
    int sel_mode = (int)hdr[1], fmode = (int)hdr[2];
    float mn = funkey(hdr[3]);
    uint32_t cnt = hdr[5];
    float M = cnt ? funkey(hdr[4]) : mn;
    float S = __uint_as_float(hdr[6]);
    float sp = sp_load(ws_sp, out, use_ws, fmode, e);
    bool selv = fetch_sel(sel, sel_mode, e);
    float masked = selv ? mn : sp;
    float r = __expf((masked - M) * 2.0f) / S;
    if (fmode) ((float*)out)[e] = r;
    else       ((uint16_t*)out)[e] = f2bf(r);
}

extern "C" void kernel_launch(void* const* d_in, const int* in_sizes, int n_in,
                              void* d_out, int out_size, void* d_ws, size_t ws_size,
                              hipStream_t stream) {
    int N = in_sizes[0] / DD;
    int E = in_sizes[1] / DD;
    const void* node = d_in[0];
    const void* edge = d_in[1];
    const void* g    = d_in[2];
    const void* sg   = d_in[3];
    const void* W    = d_in[4];
    const void* bias = d_in[5];
    const void* ei   = d_in[6];
    const void* sel  = d_in[7];

    uint8_t* ws = (uint8_t*)d_ws;
    uint32_t* hdr = (uint32_t*)ws;
    float* Wf = (float*)(ws + 256);
    float* bf = (float*)(ws + 256 + 12288);
    float* vf = (float*)(ws + 256 + 12288 + 128);
    float* sp_arr = (float*)(ws + 16384);
    int use_ws = (ws_size >= (size_t)16384 + (size_t)E * sizeof(float)) ? 1 : 0;

    int grid = (E + 255) / 256;
    k_init<<<1, 256, 0, stream>>>(W, bias, g, sg, ei, sel, hdr, Wf, bf, vf, E, N);
    k_pass1<<<grid, 256, 0, stream>>>((const char*)node, (const char*)edge, (const char*)ei,
                                      (const char*)sel, hdr, Wf, bf, vf, sp_arr, d_out,
                                      use_ws, E, N);
    k_pass2<<<grid, 256, 0, stream>>>((const char*)sel, hdr, sp_arr, d_out, use_ws, E);
    k_pass3<<<grid, 256, 0, stream>>>((const char*)sel, hdr, sp_arr, d_out, use_ws, E);
}

// Round 2
// 1043.309 us; speedup vs baseline: 1.1173x; 1.1173x over previous
//
#include <hip/hip_runtime.h>
#include <hip/hip_bf16.h>
#include <stdint.h>

#define DD 32
#define KH 96   // 3*D

// ws layout:
//  hdr (uint32):
//   [0] idx_mode  (0 = int64, 1 = int32)
//   [1] sel_mode  (0 = int64, 1 = int32, 2 = bytes)
//   [2] fmode     (0 = bf16 floats, 1 = fp32 floats)
//   [3] min_key   (encoded float, atomicMin over ALL state_prob)
//   [4] max_key   (encoded float, atomicMax over UNSELECTED state_prob)
//   [5] cnt_unsel
//   [6] sum       (float bits, atomicAdd)
//  ws+256    : float Wf[3072]
//  ws+12544  : float bf[32]
//  ws+12672  : float vf[32]
//  ws+16384  : float sp[E]   (only if ws_size permits; else sp lives in d_out)

__device__ __forceinline__ uint32_t fkey(float f) {
    uint32_t b = __float_as_uint(f);
    return (b & 0x80000000u) ? ~b : (b | 0x80000000u);
}
__device__ __forceinline__ float funkey(uint32_t k) {
    uint32_t b = (k & 0x80000000u) ? (k & 0x7FFFFFFFu) : ~k;
    return __uint_as_float(b);
}
__device__ __forceinline__ float bflo(uint32_t w) { return __uint_as_float(w << 16); }
__device__ __forceinline__ float bfhi(uint32_t w) { return __uint_as_float(w & 0xFFFF0000u); }
__device__ __forceinline__ uint16_t f2bf(float v) {
    uint32_t u = __float_as_uint(v);
    uint32_t r = (u + 0x7FFFu + ((u >> 16) & 1u)) >> 16;
    return (uint16_t)r;
}

// all-VGPR VOP2 fmac (4-byte encoding): d += a*b.  Forcing VOP2 keeps the
// fully-unrolled 3072-FMA chain at ~12KB so the per-edge body fits in I$.
#define VFMAC(d, a, b) asm("v_fmac_f32 %0, %1, %2" : "+v"(d) : "v"(a), "v"(b))

__global__ void k_init(const void* W, const void* bias, const void* g, const void* sg,
                       const void* ei, const void* sel,
                       uint32_t* hdr, float* Wf, float* bf, float* vf, int E, int N) {
    int t = threadIdx.x;
    __shared__ int sh_i32, sh_gt1, sh_odd, sh_f32;
    if (t == 0) { sh_i32 = 0; sh_gt1 = 0; sh_odd = 0; sh_f32 = 0; }
    __syncthreads();

    const uint16_t* wb = (const uint16_t*)W;
    for (int i = t; i < KH * DD; i += 256) {
        float x = bflo((uint32_t)wb[i]);
        if (!(fabsf(x) < 1e4f)) sh_f32 = 1;
    }
    const long long* ell = (const long long*)ei;
    int ns = 2048 < E ? 2048 : E;
    for (int i = t; i < ns; i += 256) {
        long long v = ell[i];
        if (v < 0 || v >= (long long)N) sh_i32 = 1;
    }
    const uint32_t* sw = (const uint32_t*)sel;
    int ns2 = 2048 < E / 4 ? 2048 : E / 4;
    for (int i = t; i < ns2; i += 256) {
        uint32_t v = sw[i];
        if (v > 1u) sh_gt1 = 1;
        if (v != 0u && (i & 1)) sh_odd = 1;
    }
    __syncthreads();
    int fmode = sh_f32;

    for (int i = t; i < KH * DD; i += 256)
        Wf[i] = fmode ? ((const float*)W)[i] : bflo((uint32_t)wb[i]);
    for (int i = t; i < DD; i += 256) {
        bf[i] = fmode ? ((const float*)bias)[i] : bflo((uint32_t)((const uint16_t*)bias)[i]);
        float gv = fmode ? ((const float*)g)[i]  : bflo((uint32_t)((const uint16_t*)g)[i]);
        float sv = fmode ? ((const float*)sg)[i] : bflo((uint32_t)((const uint16_t*)sg)[i]);
        vf[i] = gv - sv;
    }
    if (t == 0) {
        hdr[0] = (uint32_t)sh_i32;
        hdr[1] = sh_gt1 ? 2u : (sh_odd ? 1u : 0u);
        hdr[2] = (uint32_t)fmode;
        hdr[3] = 0xFFFFFFFFu;
        hdr[4] = 0u;
        hdr[5] = 0u;
        hdr[6] = 0u;
    }
}

__device__ __forceinline__ void loadrow(const char* __restrict__ p, int fmode, float* h) {
    if (fmode) {
        const float4* q = (const float4*)p;
        #pragma unroll
        for (int t = 0; t < 8; ++t) {
            float4 u = q[t];
            h[t * 4 + 0] = u.x; h[t * 4 + 1] = u.y; h[t * 4 + 2] = u.z; h[t * 4 + 3] = u.w;
        }
    } else {
        const uint4* q = (const uint4*)p;
        #pragma unroll
        for (int t = 0; t < 4; ++t) {
            uint4 u = q[t];
            h[t * 8 + 0] = bflo(u.x); h[t * 8 + 1] = bfhi(u.x);
            h[t * 8 + 2] = bflo(u.y); h[t * 8 + 3] = bfhi(u.y);
            h[t * 8 + 4] = bflo(u.z); h[t * 8 + 5] = bfhi(u.z);
            h[t * 8 + 6] = bflo(u.w); h[t * 8 + 7] = bfhi(u.w);
        }
    }
}

__device__ __forceinline__ bool fetch_sel(const char* sel, int mode, int e) {
    if (mode == 2) return ((const uint8_t*)sel)[e] != 0;
    if (mode == 1) return ((const int*)sel)[e] != 0;
    return ((const long long*)sel)[e] != 0;
}

__device__ __forceinline__ void sp_store(float* __restrict__ ws_sp, void* __restrict__ out,
                                         int use_ws, int fmode, int e, float v) {
    if (use_ws) ws_sp[e] = v;
    else if (fmode) ((float*)out)[e] = v;
    else ((uint16_t*)out)[e] = f2bf(v);
}
__device__ __forceinline__ float sp_load(const float* __restrict__ ws_sp, const void* __restrict__ out,
                                         int use_ws, int fmode, int e) {
    if (use_ws) return ws_sp[e];
    if (fmode) return ((const float*)out)[e];
    return bflo((uint32_t)((const uint16_t*)out)[e]);
}

// One W row (32 floats): prefetch row g+2 into the rotating buffer, then
// 32 FMAs on row g.  g = R*32+k is a compile-time constant after unrolling,
// so all w[][] / hh[] indices are static (no scratch).  FMA order per acc[j]
// is identical to the original kernel (k ascending, j ascending).
#define RSEC(R)                                                             \
    _Pragma("unroll")                                                       \
    for (int k = 0; k < 32; ++k) {                                          \
        const int g = (R) * 32 + k;                                         \
        if (g + 2 < 96) {                                                   \
            _Pragma("unroll")                                               \
            for (int q = 0; q < 8; ++q) w[(g + 2) % 3][q] = wq[(g + 2) * 8 + q]; \
        }                                                                   \
        float hk = hh[k];                                                   \
        _Pragma("unroll")                                                   \
        for (int q = 0; q < 8; ++q) {                                       \
            float4 c4 = w[g % 3][q];                                        \
            VFMAC(acc[q * 4 + 0], hk, c4.x);                                \
            VFMAC(acc[q * 4 + 1], hk, c4.y);                                \
            VFMAC(acc[q * 4 + 2], hk, c4.z);                                \
            VFMAC(acc[q * 4 + 3], hk, c4.w);                                \
        }                                                                   \
    }

__global__ __launch_bounds__(256, 2) void k_pass1(
    const char* __restrict__ node, const char* __restrict__ edgep,
    const char* __restrict__ ei, const char* __restrict__ sel,
    uint32_t* __restrict__ hdr, const float* __restrict__ Wf,
    const float* __restrict__ bf, const float* __restrict__ vf,
    float* __restrict__ ws_sp, void* __restrict__ out,
    int use_ws, int E, int N) {
    const int idx_mode = (int)hdr[0];
    const int sel_mode = (int)hdr[1];
    const int fmode    = (int)hdr[2];

    const float4* __restrict__ wq = (const float4*)Wf;   // 768 float4, L1-resident
    const float4* __restrict__ bq = (const float4*)bf;
    const float4* __restrict__ vq = (const float4*)vf;

    float mnA = __builtin_inff();
    float mxA = -__builtin_inff();
    uint32_t cA = 0;

    const int stride = gridDim.x * 256;
    for (int e = blockIdx.x * 256 + threadIdx.x; e < E; e += stride) {
        long long si, di;
        if (idx_mode) { si = ((const int*)ei)[e]; di = ((const int*)ei)[E + e]; }
        else          { si = ((const long long*)ei)[e]; di = ((const long long*)ei)[(size_t)E + e]; }
        int s0 = (int)si; s0 = s0 < 0 ? 0 : (s0 >= N ? N - 1 : s0);
        int d0 = (int)di; d0 = d0 < 0 ? 0 : (d0 >= N ? N - 1 : d0);

        size_t rb = fmode ? 128 : 64;
        const char* p0 = node  + (size_t)s0 * rb;
        const char* p1 = node  + (size_t)d0 * rb;
        const char* p2 = edgep + (size_t)e * rb;

        float hh[DD];
        loadrow(p0, fmode, hh);

        // acc init from bias (uniform VMEM loads; order: bias first, then +=)
        float acc[DD];
        #pragma unroll
        for (int q = 0; q < 8; ++q) {
            float4 b4 = bq[q];
            acc[q * 4 + 0] = b4.x; acc[q * 4 + 1] = b4.y;
            acc[q * 4 + 2] = b4.z; acc[q * 4 + 3] = b4.w;
        }

        // W pipeline: rotating 3-slot register buffer, prefetch distance 2
        // (~256 cycles of FMA cover per in-flight load; vmcnt is in-order so
        // the compiler emits counted waits — no full drains in the chain).
        float4 w[3][8];
        #pragma unroll
        for (int q = 0; q < 8; ++q) w[0][q] = wq[q];
        #pragma unroll
        for (int q = 0; q < 8; ++q) w[1][q] = wq[8 + q];

        RSEC(0)
        loadrow(p1, fmode, hh);
        RSEC(1)
        loadrow(p2, fmode, hh);
        RSEC(2)

        // ELU + dot with (g - sg); exact same op order as the original tail
        float vv[DD];
        #pragma unroll
        for (int q = 0; q < 8; ++q) {
            float4 v4 = vq[q];
            vv[q * 4 + 0] = v4.x; vv[q * 4 + 1] = v4.y;
            vv[q * 4 + 2] = v4.z; vv[q * 4 + 3] = v4.w;
        }
        float sp = 0.f;
        #pragma unroll
        for (int j = 0; j < 16; ++j) {
            float a = acc[j];
            float act = a > 0.f ? a : (__expf(a) - 1.f);
            sp = fmaf(act, vv[j], sp);
            float a2 = acc[16 + j];
            float act2 = a2 > 0.f ? a2 : (__expf(a2) - 1.f);
            sp = fmaf(act2, vv[16 + j], sp);
        }

        sp_store(ws_sp, out, use_ws, fmode, e, sp);
        bool selv = fetch_sel(sel, sel_mode, e);

        mnA = fminf(mnA, sp);
        mxA = selv ? mxA : fmaxf(mxA, sp);
        cA += selv ? 0u : 1u;
    }

    // block-level reduction (once per block)
    float mn = mnA, mx = mxA;
    uint32_t c = cA;
    #pragma unroll
    for (int o = 32; o >= 1; o >>= 1) {
        mn = fminf(mn, __shfl_xor(mn, o));
        mx = fmaxf(mx, __shfl_xor(mx, o));
        c += __shfl_xor(c, o);
    }
    __shared__ float smn[4], smx[4];
    __shared__ uint32_t sc[4];
    int wid = threadIdx.x >> 6, lane = threadIdx.x & 63;
    if (lane == 0) { smn[wid] = mn; smx[wid] = mx; sc[wid] = c; }
    __syncthreads();
    if (threadIdx.x == 0) {
        for (int w2 = 1; w2 < 4; ++w2) { mn = fminf(mn, smn[w2]); mx = fmaxf(mx, smx[w2]); c += sc[w2]; }
        atomicMin(&hdr[3], fkey(mn));
        atomicMax(&hdr[4], fkey(mx));
        if (c) atomicAdd(&hdr[5], c);
    }
}

__global__ __launch_bounds__(256) void k_pass2(
    const char* __restrict__ sel, uint32_t* __restrict__ hdr,
    const float* __restrict__ ws_sp, const void* __restrict__ out,
    int use_ws, int E) {
    int sel_mode = (int)hdr[1], fmode = (int)hdr[2];
    float mn = funkey(hdr[3]);
    uint32_t cnt = hdr[5];
    float M = cnt ? funkey(hdr[4]) : mn;

    float p = 0.f;
    const int stride = gridDim.x * 256;
    for (int e = blockIdx.x * 256 + threadIdx.x; e < E; e += stride) {
        float sp = sp_load(ws_sp, out, use_ws, fmode, e);
        bool selv = fetch_sel(sel, sel_mode, e);
        float masked = selv ? mn : sp;
        p += __expf((masked - M) * 2.0f);
    }
    #pragma unroll
    for (int o = 32; o >= 1; o >>= 1) p += __shfl_xor(p, o);
    __shared__ float sps[4];
    int wid = threadIdx.x >> 6, lane = threadIdx.x & 63;
    if (lane == 0) sps[wid] = p;
    __syncthreads();
    if (threadIdx.x == 0) {
        p += sps[1] + sps[2] + sps[3];
        atomicAdd((float*)&hdr[6], p);
    }
}

__global__ __launch_bounds__(256) void k_pass3(
    const char* __restrict__ sel, const uint32_t* __restrict__ hdr,
    const float* __restrict__ ws_sp, void* __restrict__ out,
    int use_ws, int E) {
    int sel_mode = (int)hdr[1], fmode = (int)hdr[2];
    float mn = funkey(hdr[3]);
    uint32_t cnt = hdr[5];
    float M = cnt ? funkey(hdr[4]) : mn;
    float S = __uint_as_float(hdr[6]);
    const int stride = gridDim.x * 256;
    for (int e = blockIdx.x * 256 + threadIdx.x; e < E; e += stride) {
        float sp = sp_load(ws_sp, out, use_ws, fmode, e);
        bool selv = fetch_sel(sel, sel_mode, e);
        float masked = selv ? mn : sp;
        float r = __expf((masked - M) * 2.0f) / S;
        if (fmode) ((float*)out)[e] = r;
        else       ((uint16_t*)out)[e] = f2bf(r);
    }
}

extern "C" void kernel_launch(void* const* d_in, const int* in_sizes, int n_in,
                              void* d_out, int out_size, void* d_ws, size_t ws_size,
                              hipStream_t stream) {
    int N = in_sizes[0] / DD;
    int E = in_sizes[1] / DD;
    const void* node = d_in[0];
    const void* edge = d_in[1];
    const void* g    = d_in[2];
    const void* sg   = d_in[3];
    const void* W    = d_in[4];
    const void* bias = d_in[5];
    const void* ei   = d_in[6];
    const void* sel  = d_in[7];

    uint8_t* ws = (uint8_t*)d_ws;
    uint32_t* hdr = (uint32_t*)ws;
    float* Wf = (float*)(ws + 256);
    float* bf = (float*)(ws + 256 + 12288);
    float* vf = (float*)(ws + 256 + 12288 + 128);
    float* sp_arr = (float*)(ws + 16384);
    int use_ws = (ws_size >= (size_t)16384 + (size_t)E * sizeof(float)) ? 1 : 0;

    // Persistent-style grids: the old 12500-WG grids were launch-rate-bound
    // (~45 WG/us => ~278 us per grid just to dispatch).
    int full = (E + 255) / 256;
    int grid1 = full < 2048 ? full : 2048;
    int grid23 = full < 1024 ? full : 1024;

    k_init<<<1, 256, 0, stream>>>(W, bias, g, sg, ei, sel, hdr, Wf, bf, vf, E, N);
    k_pass1<<<grid1, 256, 0, stream>>>((const char*)node, (const char*)edge, (const char*)ei,
                                       (const char*)sel, hdr, Wf, bf, vf, sp_arr, d_out,
                                       use_ws, E, N);
    k_pass2<<<grid23, 256, 0, stream>>>((const char*)sel, hdr, sp_arr, d_out, use_ws, E);
    k_pass3<<<grid23, 256, 0, stream>>>((const char*)sel, hdr, sp_arr, d_out, use_ws, E);
}